// Round 1
// baseline (1425.384 us; speedup 1.0000x reference)
//
#include <hip/hip_runtime.h>

#define NU 100000
#define NI 100000
#define NT 200000
#define D 64
#define NLAYERS 3
#define NNZ_TOTAL 3200000
#define ALPHA 0.2f

// ---------------- init: E = concat(user_table[uidx], item_table[iidx]) ----------------
__global__ __launch_bounds__(256) void init_emb_kernel(
    const float* __restrict__ ut, const float* __restrict__ it,
    const int* __restrict__ uidx, const int* __restrict__ iidx,
    float* __restrict__ E)
{
    int i = blockIdx.x * 256 + threadIdx.x;          // element index, NT*64 = 12.8M < 2^31
    if (i >= NT * D) return;
    int n = i >> 6;
    int d = i & 63;
    float v;
    if (n < NU) v = ut[uidx[n] * D + d];
    else        v = it[iidx[n - NU] * D + d];
    E[i] = v;
}

// ---------------- CSR build ----------------
__global__ __launch_bounds__(256) void hist_kernel(const int* __restrict__ rows,
                                                   int* __restrict__ counts)
{
    int i = blockIdx.x * 256 + threadIdx.x;
    if (i < NNZ_TOTAL) atomicAdd(&counts[rows[i]], 1);
}

// pass A: per-block (1024 elems) totals
__global__ __launch_bounds__(256) void scan_block_tot(const int* __restrict__ counts,
                                                      int* __restrict__ btot)
{
    __shared__ int s[256];
    int b = blockIdx.x, t = threadIdx.x;
    int base = b * 1024 + t * 4;
    int sum = 0;
#pragma unroll
    for (int j = 0; j < 4; ++j) { int idx = base + j; if (idx < NT) sum += counts[idx]; }
    s[t] = sum; __syncthreads();
    for (int off = 128; off > 0; off >>= 1) {
        if (t < off) s[t] += s[t + off];
        __syncthreads();
    }
    if (t == 0) btot[b] = s[0];
}

// pass B: single-block exclusive scan of block totals (nb <= 256)
__global__ __launch_bounds__(256) void scan_btot(const int* __restrict__ btot,
                                                 int* __restrict__ boff,
                                                 int* __restrict__ row_ptr, int nb)
{
    __shared__ int s[256];
    int t = threadIdx.x;
    int v = (t < nb) ? btot[t] : 0;
    s[t] = v; __syncthreads();
    for (int off = 1; off < 256; off <<= 1) {
        int x = (t >= off) ? s[t - off] : 0;
        __syncthreads();
        s[t] += x;
        __syncthreads();
    }
    boff[t] = s[t] - v;                 // exclusive
    if (t == 255) row_ptr[NT] = s[255]; // grand total (= NNZ_TOTAL)
}

// pass C: full exclusive scan -> row_ptr
__global__ __launch_bounds__(256) void scan_final(const int* __restrict__ counts,
                                                  const int* __restrict__ boff,
                                                  int* __restrict__ row_ptr)
{
    __shared__ int s[256];
    int b = blockIdx.x, t = threadIdx.x;
    int base = b * 1024 + t * 4;
    int c[4];
#pragma unroll
    for (int j = 0; j < 4; ++j) { int idx = base + j; c[j] = (idx < NT) ? counts[idx] : 0; }
    int tt = c[0] + c[1] + c[2] + c[3];
    s[t] = tt; __syncthreads();
    for (int off = 1; off < 256; off <<= 1) {
        int x = (t >= off) ? s[t - off] : 0;
        __syncthreads();
        s[t] += x;
        __syncthreads();
    }
    int ex = boff[b] + s[t] - tt;
#pragma unroll
    for (int j = 0; j < 4; ++j) {
        int idx = base + j;
        if (idx < NT) row_ptr[idx] = ex;
        ex += c[j];
    }
}

__global__ __launch_bounds__(256) void scatter_kernel(
    const int* __restrict__ rows, const int* __restrict__ cols,
    const float* __restrict__ vals, const int* __restrict__ row_ptr,
    int* __restrict__ cursor, int* __restrict__ csr_col, float* __restrict__ csr_val)
{
    int i = blockIdx.x * 256 + threadIdx.x;
    if (i >= NNZ_TOTAL) return;
    int r = rows[i];
    int pos = row_ptr[r] + atomicAdd(&cursor[r], 1);
    csr_col[pos] = cols[i];
    csr_val[pos] = vals[i];
}

// ---------------- SpMM: R[r] = sum val * E[col], wave per row, lane = dim ----------------
__global__ __launch_bounds__(256) void spmm_kernel(
    const float* __restrict__ E, const int* __restrict__ row_ptr,
    const int* __restrict__ csr_col, const float* __restrict__ csr_val,
    float* __restrict__ R)
{
    int w = (blockIdx.x * 256 + threadIdx.x) >> 6;   // row
    int lane = threadIdx.x & 63;
    if (w >= NT) return;
    int beg = row_ptr[w], end = row_ptr[w + 1];
    float acc = 0.f;
    int j = beg;
    for (; j + 4 <= end; j += 4) {
        int   c0 = csr_col[j],     c1 = csr_col[j + 1], c2 = csr_col[j + 2], c3 = csr_col[j + 3];
        float v0 = csr_val[j],     v1 = csr_val[j + 1], v2 = csr_val[j + 2], v3 = csr_val[j + 3];
        float e0 = E[c0 * D + lane], e1 = E[c1 * D + lane];
        float e2 = E[c2 * D + lane], e3 = E[c3 * D + lane];
        acc += v0 * e0; acc += v1 * e1; acc += v2 * e2; acc += v3 * e3;
    }
    for (; j < end; ++j) acc += csr_val[j] * E[csr_col[j] * D + lane];
    R[w * D + lane] = acc;
}

// ---------------- dense: E <- leakyrelu(R @ W1 + (R .* E) @ W2), in place ----------------
// Persistent waves; each wave holds both 64x64 weight matrices (column = lane) in VGPRs.
__global__ __launch_bounds__(256) void dense_kernel(
    const float* __restrict__ R, float* __restrict__ E,
    const float* __restrict__ W1, const float* __restrict__ W2)
{
    __shared__ float2 sAM[4][64];
    int t = threadIdx.x;
    int lane = t & 63;
    int wl = t >> 6;
    float w1r[64], w2r[64];
#pragma unroll
    for (int k = 0; k < 64; ++k) {
        w1r[k] = W1[k * 64 + lane];
        w2r[k] = W2[k * 64 + lane];
    }
    int gw = blockIdx.x * 4 + wl;
    int stride = gridDim.x * 4;
    for (int r = gw; r < NT; r += stride) {
        float a = R[r * 64 + lane];
        float e = E[r * 64 + lane];
        float m = a * e;
        sAM[wl][lane] = make_float2(a, m);   // wave-private slice; no barrier needed
        float o = 0.f;
#pragma unroll
        for (int k = 0; k < 64; ++k) {
            float2 am = sAM[wl][k];          // broadcast read
            o += am.x * w1r[k] + am.y * w2r[k];
        }
        o = o > 0.f ? o : ALPHA * o;
        E[r * 64 + lane] = o;
    }
}

// ---------------- per-stage dot: out[n] (+)= dot(E[n], E[NU+n]) ----------------
__global__ __launch_bounds__(256) void dot_kernel(const float* __restrict__ E,
                                                  float* __restrict__ out, int first)
{
    int w = (blockIdx.x * 256 + threadIdx.x) >> 6;   // user index
    int lane = threadIdx.x & 63;
    if (w >= NU) return;
    float p = E[w * 64 + lane] * E[(NU + w) * 64 + lane];
#pragma unroll
    for (int off = 32; off > 0; off >>= 1) p += __shfl_xor(p, off);
    if (lane == 0) {
        if (first) out[w] = p;
        else       out[w] += p;
    }
}

extern "C" void kernel_launch(void* const* d_in, const int* in_sizes, int n_in,
                              void* d_out, int out_size, void* d_ws, size_t ws_size,
                              hipStream_t stream)
{
    const float* ut   = (const float*)d_in[0];
    const float* it   = (const float*)d_in[1];
    const float* W1   = (const float*)d_in[2];
    const float* W2   = (const float*)d_in[3];
    const float* vals = (const float*)d_in[4];
    const int*   rows = (const int*)d_in[5];
    const int*   cols = (const int*)d_in[6];
    const int*   uidx = (const int*)d_in[7];
    const int*   iidx = (const int*)d_in[8];
    float* out = (float*)d_out;

    char* ws = (char*)d_ws;
    float* E       = (float*)(ws + 0);           // 51,200,000 B
    float* R       = (float*)(ws + 51200000);    // 51,200,000 B
    int*   counts  = (int*)  (ws + 102400000);   // 800,000 B
    int*   cursor  = (int*)  (ws + 103200000);   // 800,000 B
    int*   row_ptr = (int*)  (ws + 104000000);   // 800,004 B (padded to 104,800,256)
    int*   btot    = (int*)  (ws + 104800256);   // 1024 B
    int*   boff    = (int*)  (ws + 104801280);   // 1024 B
    int*   csr_col = (int*)  (ws + 104802304);   // 12,800,000 B
    float* csr_val = (float*)(ws + 117602304);   // 12,800,000 B -> end 130,402,304

    hipMemsetAsync(counts, 0, NT * 4, stream);
    hipMemsetAsync(cursor, 0, NT * 4, stream);

    init_emb_kernel<<<(NT * D) / 256, 256, 0, stream>>>(ut, it, uidx, iidx, E);

    hist_kernel<<<(NNZ_TOTAL + 255) / 256, 256, 0, stream>>>(rows, counts);
    const int NB = (NT + 1023) / 1024;           // 196
    scan_block_tot<<<NB, 256, 0, stream>>>(counts, btot);
    scan_btot<<<1, 256, 0, stream>>>(btot, boff, row_ptr, NB);
    scan_final<<<NB, 256, 0, stream>>>(counts, boff, row_ptr);
    scatter_kernel<<<(NNZ_TOTAL + 255) / 256, 256, 0, stream>>>(rows, cols, vals, row_ptr,
                                                                cursor, csr_col, csr_val);

    dot_kernel<<<NU / 4, 256, 0, stream>>>(E, out, 1);   // stage 0

    for (int l = 0; l < NLAYERS; ++l) {
        spmm_kernel<<<NT / 4, 256, 0, stream>>>(E, row_ptr, csr_col, csr_val, R);
        dense_kernel<<<512, 256, 0, stream>>>(R, E, W1 + l * 4096, W2 + l * 4096);
        dot_kernel<<<NU / 4, 256, 0, stream>>>(E, out, 0);
    }
}